// Round 1
// baseline (522.438 us; speedup 1.0000x reference)
//
#include <hip/hip_runtime.h>
#include <hip/hip_bf16.h>

// Problem constants (from reference):
//   B=256, d=2048, N0=7936, N=N0+B=8192, K=128, P=2, ALPHA=BETA=1, EPS=1e-12
#define BDIM   256
#define DDIM   2048
#define NGAL   7936
#define NTOT   8192
#define TOPK   128
#define EPSC   1e-12f

// ---------------- Kernel 1: squares + feature norms -------------------------
// ft = f_t^2, fs = f_s^2, ftnorm[b]=sum(ft^2), fsnorm[b]=sum(fs^2),
// galnorm[NGAL+b] = ftnorm[b]
__global__ __launch_bounds__(256) void k_sqnorm(
    const float* __restrict__ f_t, const float* __restrict__ f_s,
    float* __restrict__ ft, float* __restrict__ fs,
    float* __restrict__ ftnorm, float* __restrict__ fsnorm,
    float* __restrict__ galnorm) {
  int b = blockIdx.x, t = threadIdx.x;
  const float4* t4 = (const float4*)(f_t + b * DDIM);
  const float4* s4 = (const float4*)(f_s + b * DDIM);
  float4* ft4 = (float4*)(ft + b * DDIM);
  float4* fs4 = (float4*)(fs + b * DDIM);
  float sumt = 0.f, sums = 0.f;
  for (int i = t; i < DDIM / 4; i += 256) {
    float4 v = t4[i];
    float4 q = make_float4(v.x * v.x, v.y * v.y, v.z * v.z, v.w * v.w);
    ft4[i] = q;
    sumt += q.x * q.x + q.y * q.y + q.z * q.z + q.w * q.w;
    float4 u = s4[i];
    float4 r = make_float4(u.x * u.x, u.y * u.y, u.z * u.z, u.w * u.w);
    fs4[i] = r;
    sums += r.x * r.x + r.y * r.y + r.z * r.z + r.w * r.w;
  }
  for (int off = 32; off; off >>= 1) {
    sumt += __shfl_xor(sumt, off);
    sums += __shfl_xor(sums, off);
  }
  __shared__ float red[8];
  int lane = t & 63, w = t >> 6;
  if (lane == 0) { red[w] = sumt; red[4 + w] = sums; }
  __syncthreads();
  if (t == 0) {
    float st = red[0] + red[1] + red[2] + red[3];
    float ss = red[4] + red[5] + red[6] + red[7];
    ftnorm[b] = st;
    galnorm[NGAL + b] = st;
    fsnorm[b] = ss;
  }
}

// ---------------- Kernel 2: gallery norms -----------------------------------
__global__ __launch_bounds__(256) void k_galnorm(
    const float* __restrict__ gallery, float* __restrict__ galnorm) {
  int n = blockIdx.x, t = threadIdx.x;
  const float4* g4 = (const float4*)(gallery + (size_t)n * DDIM);
  float s = 0.f;
  for (int i = t; i < DDIM / 4; i += 256) {
    float4 v = g4[i];
    s += v.x * v.x + v.y * v.y + v.z * v.z + v.w * v.w;
  }
  for (int off = 32; off; off >>= 1) s += __shfl_xor(s, off);
  __shared__ float red[4];
  int lane = t & 63, w = t >> 6;
  if (lane == 0) red[w] = s;
  __syncthreads();
  if (t == 0) galnorm[n] = red[0] + red[1] + red[2] + red[3];
}

// ---------------- Kernel 3: fp32 GEMM -> clipped squared distance ----------
// d2[b][n] = max(ftnorm[b] + galnorm[n] - 2 * ft_b . gal_n, EPS)
// gal row n: gallery[n] for n<NGAL else ft[n-NGAL]
#define BM 64
#define BN 128
#define BK 16
__global__ __launch_bounds__(256) void k_gemm_d2(
    const float* __restrict__ ft, const float* __restrict__ gallery,
    const float* __restrict__ ftnorm, const float* __restrict__ galnorm,
    float* __restrict__ d2) {
  __shared__ float As[BK][BM];
  __shared__ float Bs[BK][BN];
  int t = threadIdx.x;
  int n0 = blockIdx.x * BN;
  int m0 = blockIdx.y * BM;
  int tx = t & 15, ty = t >> 4;   // tx: 8 cols each, ty: 4 rows each
  float acc[4][8] = {};
  int arow = t >> 2, ak0 = (t & 3) * 4;
  for (int kt = 0; kt < DDIM; kt += BK) {
    __syncthreads();
    {
      float4 av = *(const float4*)(ft + (m0 + arow) * DDIM + kt + ak0);
      As[ak0 + 0][arow] = av.x; As[ak0 + 1][arow] = av.y;
      As[ak0 + 2][arow] = av.z; As[ak0 + 3][arow] = av.w;
#pragma unroll
      for (int p = 0; p < 2; ++p) {
        int f = t + p * 256;
        int brow = f >> 2, bk0 = (f & 3) * 4;
        int n = n0 + brow;
        const float* bp = (n < NGAL) ? (gallery + (size_t)n * DDIM)
                                     : (ft + (size_t)(n - NGAL) * DDIM);
        float4 bv = *(const float4*)(bp + kt + bk0);
        Bs[bk0 + 0][brow] = bv.x; Bs[bk0 + 1][brow] = bv.y;
        Bs[bk0 + 2][brow] = bv.z; Bs[bk0 + 3][brow] = bv.w;
      }
    }
    __syncthreads();
#pragma unroll
    for (int k = 0; k < BK; ++k) {
      float a[4], bb[8];
      *(float4*)a = *(const float4*)&As[k][ty * 4];
      *(float4*)(bb + 0) = *(const float4*)&Bs[k][tx * 8];
      *(float4*)(bb + 4) = *(const float4*)&Bs[k][tx * 8 + 4];
#pragma unroll
      for (int i = 0; i < 4; ++i)
#pragma unroll
        for (int j = 0; j < 8; ++j) acc[i][j] += a[i] * bb[j];
    }
  }
#pragma unroll
  for (int i = 0; i < 4; ++i) {
    int m = m0 + ty * 4 + i;
    float fn = ftnorm[m];
    float ov[8];
#pragma unroll
    for (int j = 0; j < 8; ++j) {
      int n = n0 + tx * 8 + j;
      ov[j] = fmaxf(fn + galnorm[n] - 2.0f * acc[i][j], EPSC);
    }
    float* dst = d2 + (size_t)m * NTOT + n0 + tx * 8;
    *(float4*)(dst + 0) = *(float4*)(ov + 0);
    *(float4*)(dst + 4) = *(float4*)(ov + 4);
  }
}

// ---------------- Kernel 4: per-row top-128 via full bitonic sort ----------
// keys = (f32bits(d2) << 32) | idx ; ascending sort == ascending distance,
// ties broken by lower index (matches top_k tie behavior).
__global__ __launch_bounds__(256) void k_topk(
    const float* __restrict__ d2, float* __restrict__ t_value,
    int* __restrict__ topidx) {
  extern __shared__ unsigned long long keys[];
  int b = blockIdx.x, t = threadIdx.x;
  const float* row = d2 + (size_t)b * NTOT;
  for (int i = t; i < NTOT; i += 256) {
    unsigned u = __float_as_uint(row[i]);  // all values > 0
    keys[i] = ((unsigned long long)u << 32) | (unsigned)i;
  }
  for (int len = 2; len <= NTOT; len <<= 1) {
    for (int inc = len >> 1; inc > 0; inc >>= 1) {
      __syncthreads();
      for (int idx = t; idx < NTOT / 2; idx += 256) {
        int low = idx & (inc - 1);
        int i = ((idx - low) << 1) + low;
        int j = i + inc;
        unsigned long long a = keys[i], c = keys[j];
        bool asc = ((i & len) == 0);
        if ((a > c) == asc) { keys[i] = c; keys[j] = a; }
      }
    }
  }
  __syncthreads();
  if (t < TOPK) {
    unsigned long long kk = keys[t];
    t_value[b * TOPK + t] = sqrtf(__uint_as_float((unsigned)(kk >> 32)));
    topidx[b * TOPK + t] = (int)(unsigned)kk;
  }
}

// ---------------- Kernel 5: student distances to gathered rows -------------
__global__ __launch_bounds__(256) void k_svalue(
    const float* __restrict__ fs, const float* __restrict__ gallery,
    const float* __restrict__ ft, const int* __restrict__ topidx,
    const float* __restrict__ fsnorm, const float* __restrict__ galnorm,
    float* __restrict__ s_value) {
  int b = blockIdx.x;
  int lane = threadIdx.x & 63, w = threadIdx.x >> 6;
  const float4* fs4 = (const float4*)(fs + b * DDIM);
  float4 fv[8];
#pragma unroll
  for (int i = 0; i < 8; ++i) fv[i] = fs4[i * 64 + lane];
  float fn = fsnorm[b];
  for (int it = 0; it < TOPK / 4; ++it) {
    int k = it * 4 + w;
    int rown = topidx[b * TOPK + k];
    const float4* g4 = (rown < NGAL)
                           ? (const float4*)(gallery + (size_t)rown * DDIM)
                           : (const float4*)(ft + (size_t)(rown - NGAL) * DDIM);
    float acc = 0.f;
#pragma unroll
    for (int i = 0; i < 8; ++i) {
      float4 g = g4[i * 64 + lane];
      acc += fv[i].x * g.x + fv[i].y * g.y + fv[i].z * g.z + fv[i].w * g.w;
    }
    for (int off = 32; off; off >>= 1) acc += __shfl_xor(acc, off);
    if (lane == 0) {
      float v = fn + galnorm[rown] - 2.f * acc;
      s_value[b * TOPK + k] = sqrtf(fmaxf(v, EPSC));
    }
  }
}

// ---------------- Kernel 6: smooth-rank + loss -----------------------------
__global__ __launch_bounds__(128) void k_loss(
    const float* __restrict__ t_value, const float* __restrict__ s_value,
    float* __restrict__ out) {
  __shared__ float tv[127], sv[127], red[2];
  int b = blockIdx.x, t = threadIdx.x;
  if (t < 127) {
    tv[t] = t_value[b * TOPK + 1 + t];
    sv[t] = s_value[b * TOPK + 1 + t];
  }
  __syncthreads();
  float val = 0.f;
  if (t < 127) {
    float ti = tv[t], si = sv[t], tr = 0.f, sr = 0.f;
    for (int j = 0; j < 127; ++j) {
      tr += fmaxf(ti - tv[j], 0.f);
      sr += fmaxf(si - sv[j], 0.f);
    }
    float d = tr - sr;
    val = d * d;
  }
  for (int off = 32; off; off >>= 1) val += __shfl_xor(val, off);
  int lane = t & 63, w = t >> 6;
  if (lane == 0) red[w] = val;
  __syncthreads();
  if (t == 0) {
    float sum = red[0] + red[1];
    float contrib =
        (1.0f / 256.0f) * fabsf(s_value[b * TOPK] - t_value[b * TOPK]) +
        (1.0f / (127.0f * 256.0f)) * sqrtf(sum);
    atomicAdd(out, contrib);
  }
}

// ---------------- launch ----------------------------------------------------
extern "C" void kernel_launch(void* const* d_in, const int* in_sizes, int n_in,
                              void* d_out, int out_size, void* d_ws,
                              size_t ws_size, hipStream_t stream) {
  const float* f_s = (const float*)d_in[0];
  const float* f_t = (const float*)d_in[1];
  const float* gallery = (const float*)d_in[2];
  float* out = (float*)d_out;
  float* ws = (float*)d_ws;

  // workspace layout (floats): ~13 MB total
  float* ft = ws;                         // 524288
  float* fs = ft + BDIM * DDIM;           // 524288
  float* ftnorm = fs + BDIM * DDIM;       // 256
  float* fsnorm = ftnorm + BDIM;          // 256
  float* galnorm = fsnorm + BDIM;         // 8192
  float* d2 = galnorm + NTOT;             // 2097152
  int* topidx = (int*)(d2 + (size_t)BDIM * NTOT);  // 32768
  float* t_value = (float*)(topidx + BDIM * TOPK); // 32768
  float* s_value = t_value + BDIM * TOPK;          // 32768

  hipMemsetAsync(d_out, 0, sizeof(float), stream);

  k_sqnorm<<<BDIM, 256, 0, stream>>>(f_t, f_s, ft, fs, ftnorm, fsnorm, galnorm);
  k_galnorm<<<NGAL, 256, 0, stream>>>(gallery, galnorm);
  dim3 g3(NTOT / BN, BDIM / BM);
  k_gemm_d2<<<g3, 256, 0, stream>>>(ft, gallery, ftnorm, galnorm, d2);
  k_topk<<<BDIM, 256, NTOT * sizeof(unsigned long long), stream>>>(d2, t_value,
                                                                   topidx);
  k_svalue<<<BDIM, 256, 0, stream>>>(fs, gallery, ft, topidx, fsnorm, galnorm,
                                     s_value);
  k_loss<<<BDIM, 128, 0, stream>>>(t_value, s_value, out);
}

// Round 2
// 182.246 us; speedup vs baseline: 2.8667x; 2.8667x over previous
//
#include <hip/hip_runtime.h>
#include <hip/hip_bf16.h>

// B=256, d=2048, N0=7936, N=8192, K=128, P=2, ALPHA=BETA=1, EPS=1e-12
#define BDIM 256
#define DDIM 2048
#define NGAL 7936
#define NTOT 8192
#define TOPK 128
#define EPSC 1e-12f

typedef __attribute__((ext_vector_type(8))) short bf16x8;
typedef __attribute__((ext_vector_type(4))) float f32x4;
typedef unsigned long long u64;

// round-to-nearest-even fp32 -> bf16 (bit pattern in a short)
__device__ __forceinline__ short bfr(float x) {
  unsigned u = __float_as_uint(x);
  unsigned r = (u + 0x7FFFu + ((u >> 16) & 1u)) >> 16;
  return (short)r;
}

// ---------------- Kernel 1: teacher/student squares, norms, bf16 A rows ----
// A = [ft; fs] (512 x 2048) bf16; B rows [NGAL..NTOT) = ft bf16.
// normA[b] = sum(ft^2) (fp32), normA[256+b] = sum(fs^2); galnorm[NGAL+b]=normA[b]
__global__ __launch_bounds__(256) void k_prep(
    const float* __restrict__ f_t, const float* __restrict__ f_s,
    short* __restrict__ Abf, short* __restrict__ Bbf,
    float* __restrict__ normA, float* __restrict__ galnorm) {
  int b = blockIdx.x, t = threadIdx.x;
  const float4* t4 = (const float4*)(f_t + (size_t)b * DDIM);
  const float4* s4 = (const float4*)(f_s + (size_t)b * DDIM);
  float st = 0.f, ss = 0.f;
  for (int i = t; i < DDIM / 4; i += 256) {
    float4 v = t4[i];
    float4 q = make_float4(v.x * v.x, v.y * v.y, v.z * v.z, v.w * v.w);
    short4 qb = make_short4(bfr(q.x), bfr(q.y), bfr(q.z), bfr(q.w));
    *(short4*)&Abf[(size_t)b * DDIM + i * 4] = qb;
    *(short4*)&Bbf[(size_t)(NGAL + b) * DDIM + i * 4] = qb;
    st += q.x * q.x + q.y * q.y + q.z * q.z + q.w * q.w;
    float4 u_ = s4[i];
    float4 r = make_float4(u_.x * u_.x, u_.y * u_.y, u_.z * u_.z, u_.w * u_.w);
    *(short4*)&Abf[(size_t)(BDIM + b) * DDIM + i * 4] =
        make_short4(bfr(r.x), bfr(r.y), bfr(r.z), bfr(r.w));
    ss += r.x * r.x + r.y * r.y + r.z * r.z + r.w * r.w;
  }
  for (int off = 32; off; off >>= 1) {
    st += __shfl_xor(st, off);
    ss += __shfl_xor(ss, off);
  }
  __shared__ float red[8];
  int lane = t & 63, wv = t >> 6;
  if (lane == 0) { red[wv] = st; red[4 + wv] = ss; }
  __syncthreads();
  if (t == 0) {
    float a = red[0] + red[1] + red[2] + red[3];
    float c = red[4] + red[5] + red[6] + red[7];
    normA[b] = a;
    galnorm[NGAL + b] = a;
    normA[BDIM + b] = c;
  }
}

// ---------------- Kernel 2: gallery -> bf16 rows + norms (1 wave/row) ------
__global__ __launch_bounds__(256) void k_galn(
    const float* __restrict__ gallery, short* __restrict__ Bbf,
    float* __restrict__ galnorm) {
  int row = blockIdx.x * 4 + (threadIdx.x >> 6);
  int lane = threadIdx.x & 63;
  const float4* g4 = (const float4*)(gallery + (size_t)row * DDIM);
  float s = 0.f;
  for (int i = lane; i < DDIM / 4; i += 64) {
    float4 v = g4[i];
    *(short4*)&Bbf[(size_t)row * DDIM + i * 4] =
        make_short4(bfr(v.x), bfr(v.y), bfr(v.z), bfr(v.w));
    s += v.x * v.x + v.y * v.y + v.z * v.z + v.w * v.w;
  }
  for (int off = 32; off; off >>= 1) s += __shfl_xor(s, off);
  if (lane == 0) galnorm[row] = s;
}

// ---------------- Kernel 3: bf16 MFMA GEMM -> clipped squared distances ----
// C[m][n] = sum_k A[m][k]*B[n][k]; d2[m][n] = clamp(normA[m]+galnorm[n]-2C, EPS)
// Pin d2[m][NGAL+m] = EPS for teacher rows (exact self-match).
// 128x128 tile, BK=64, 4 waves (2x2), double-buffered swizzled LDS.
__global__ __launch_bounds__(256) void k_gemm(
    const short* __restrict__ Abf, const short* __restrict__ Bbf,
    const float* __restrict__ normA, const float* __restrict__ galnorm,
    float* __restrict__ d2) {
  __shared__ short As[2][128 * 64];
  __shared__ short Bs[2][128 * 64];
  int t = threadIdx.x;
  int n0 = blockIdx.x * 128, m0 = blockIdx.y * 128;
  int lane = t & 63, wid = t >> 6;
  int wm = wid >> 1, wn = wid & 1;

  const short* Ag = Abf + (size_t)m0 * DDIM;
  const short* Bg = Bbf + (size_t)n0 * DDIM;

  // staging: chunk c = t + q*256 -> row r = c>>3 in tile, 16B unit j = c&7
  int j = t & 7, rb_ = t >> 3;
  size_t gofs = (size_t)rb_ * DDIM + j * 8;                // + q*32*DDIM + kt
  int lofs = rb_ * 64 + ((j * 8) ^ ((rb_ & 7) << 3));      // + q*2048 (swizzled)

  // fragment addressing
  int fr = lane & 15, fk = (lane >> 4) * 8;
  int axor = (fr & 7) << 3;

  f32x4 acc[4][4] = {};
  bf16x8 ra[4], rbv[4];

#pragma unroll
  for (int q = 0; q < 4; ++q) {
    ra[q] = *(const bf16x8*)(Ag + gofs + (size_t)q * 32 * DDIM);
    rbv[q] = *(const bf16x8*)(Bg + gofs + (size_t)q * 32 * DDIM);
  }
#pragma unroll
  for (int q = 0; q < 4; ++q) {
    *(bf16x8*)&As[0][lofs + q * 2048] = ra[q];
    *(bf16x8*)&Bs[0][lofs + q * 2048] = rbv[q];
  }
  int cur = 0;
  for (int kt = 0; kt < DDIM; kt += 64) {
    __syncthreads();  // staged writes to buf[cur] visible
    bool more = (kt + 64) < DDIM;
    if (more) {
#pragma unroll
      for (int q = 0; q < 4; ++q) {
        ra[q] = *(const bf16x8*)(Ag + gofs + (size_t)q * 32 * DDIM + kt + 64);
        rbv[q] = *(const bf16x8*)(Bg + gofs + (size_t)q * 32 * DDIM + kt + 64);
      }
    }
#pragma unroll
    for (int ks = 0; ks < 2; ++ks) {
      int ko = (ks * 32 + fk) ^ axor;
      bf16x8 av[4], bv[4];
#pragma unroll
      for (int mi = 0; mi < 4; ++mi)
        av[mi] = *(const bf16x8*)&As[cur][(wm * 64 + mi * 16 + fr) * 64 + ko];
#pragma unroll
      for (int ni = 0; ni < 4; ++ni)
        bv[ni] = *(const bf16x8*)&Bs[cur][(wn * 64 + ni * 16 + fr) * 64 + ko];
#pragma unroll
      for (int mi = 0; mi < 4; ++mi)
#pragma unroll
        for (int ni = 0; ni < 4; ++ni)
          acc[mi][ni] = __builtin_amdgcn_mfma_f32_16x16x32_bf16(
              av[mi], bv[ni], acc[mi][ni], 0, 0, 0);
    }
    __syncthreads();  // reads of buf[cur] done
    if (more) {
      cur ^= 1;
#pragma unroll
      for (int q = 0; q < 4; ++q) {
        *(bf16x8*)&As[cur][lofs + q * 2048] = ra[q];
        *(bf16x8*)&Bs[cur][lofs + q * 2048] = rbv[q];
      }
    }
  }
  // epilogue: C/D layout col=lane&15, row=(lane>>4)*4+reg  [verified m89]
  int rrow = (lane >> 4) * 4;
#pragma unroll
  for (int mi = 0; mi < 4; ++mi) {
#pragma unroll
    for (int r = 0; r < 4; ++r) {
      int m = m0 + wm * 64 + mi * 16 + rrow + r;
      float nm = normA[m];
#pragma unroll
      for (int ni = 0; ni < 4; ++ni) {
        int n = n0 + wn * 64 + ni * 16 + fr;
        float v = nm + galnorm[n] - 2.0f * acc[mi][ni][r];
        v = fmaxf(v, EPSC);
        if (m < BDIM && n == NGAL + m) v = EPSC;  // exact self-match pin
        d2[(size_t)m * NTOT + n] = v;
      }
    }
  }
}

// ---------------- Kernel 4: per-row top-128 via radix select ---------------
// Exact: finds the 128th-smallest u32 bit pattern (positive floats are
// order-isomorphic to their bits), collects all <=, sorts (val,idx) keys.
__global__ __launch_bounds__(256) void k_topk(
    const float* __restrict__ d2, float* __restrict__ t_value,
    int* __restrict__ topidx) {
  __shared__ float rowv[NTOT];        // 32 KB
  __shared__ unsigned hist[4][256];   // per-wave copies
  __shared__ unsigned scan[256];
  __shared__ u64 cand[256];
  __shared__ unsigned s_pref, s_kneed, s_cnt;
  int b = blockIdx.x, t = threadIdx.x, w = t >> 6;
  const float4* row4 = (const float4*)(d2 + (size_t)b * NTOT);
  float4* rv4 = (float4*)rowv;
  for (int i = t; i < NTOT / 4; i += 256) rv4[i] = row4[i];
  if (t == 0) { s_pref = 0; s_kneed = TOPK; s_cnt = 0; }
  __syncthreads();
#pragma unroll 1
  for (int pass = 0; pass < 4; ++pass) {
    int shift = 24 - 8 * pass;
    unsigned prefmask = pass ? (0xFFFFFFFFu << (shift + 8)) : 0u;
    for (int i = t; i < 1024; i += 256) (&hist[0][0])[i] = 0;
    __syncthreads();
    unsigned pref = s_pref, kn = s_kneed;
    for (int i = t; i < NTOT; i += 256) {
      unsigned u = __float_as_uint(rowv[i]);
      if ((u & prefmask) == pref)
        atomicAdd(&hist[w][(u >> shift) & 255], 1u);
    }
    __syncthreads();
    unsigned h = hist[0][t] + hist[1][t] + hist[2][t] + hist[3][t];
    scan[t] = h;
    __syncthreads();
    for (int off = 1; off < 256; off <<= 1) {  // inclusive Hillis-Steele
      unsigned v_ = (t >= off) ? scan[t - off] : 0u;
      __syncthreads();
      scan[t] += v_;
      __syncthreads();
    }
    unsigned incl = scan[t], excl = incl - h;
    if (excl < kn && kn <= incl) {  // exactly one winner bin
      s_pref = pref | ((unsigned)t << shift);
      s_kneed = kn - excl;
    }
    __syncthreads();
  }
  unsigned ustar = s_pref;
  for (int i = t; i < NTOT; i += 256) {
    unsigned u = __float_as_uint(rowv[i]);
    if (u <= ustar) {
      unsigned p = atomicAdd(&s_cnt, 1u);
      if (p < 256) cand[p] = ((u64)u << 32) | (unsigned)i;
    }
  }
  __syncthreads();
  unsigned cnt = s_cnt;
  if (cnt > 256) cnt = 256;
  if (t >= (int)cnt) cand[t] = ~0ULL;
  __syncthreads();
  for (int len = 2; len <= 256; len <<= 1) {  // bitonic sort 256 u64 keys
    for (int inc = len >> 1; inc; inc >>= 1) {
      if (t < 128) {
        int low = t & (inc - 1);
        int i0 = ((t - low) << 1) + low, i1 = i0 + inc;
        u64 a = cand[i0], c = cand[i1];
        bool asc = ((i0 & len) == 0);
        if ((a > c) == asc) { cand[i0] = c; cand[i1] = a; }
      }
      __syncthreads();
    }
  }
  if (t < TOPK) {
    u64 kk = cand[t];
    t_value[b * TOPK + t] = sqrtf(__uint_as_float((unsigned)(kk >> 32)));
    topidx[b * TOPK + t] = (int)(unsigned)kk;
  }
}

// ---------------- Kernel 5: gather student distances -----------------------
__global__ __launch_bounds__(128) void k_sg(
    const float* __restrict__ d2, const int* __restrict__ topidx,
    float* __restrict__ s_value) {
  int b = blockIdx.x, t = threadIdx.x;
  int idx = topidx[b * TOPK + t];
  s_value[b * TOPK + t] = sqrtf(d2[(size_t)(BDIM + b) * NTOT + idx]);
}

// ---------------- Kernel 6: smooth-rank + loss -----------------------------
__global__ __launch_bounds__(128) void k_loss(
    const float* __restrict__ t_value, const float* __restrict__ s_value,
    float* __restrict__ out) {
  __shared__ float tv[127], sv[127], red[2];
  int b = blockIdx.x, t = threadIdx.x;
  if (t < 127) {
    tv[t] = t_value[b * TOPK + 1 + t];
    sv[t] = s_value[b * TOPK + 1 + t];
  }
  __syncthreads();
  float val = 0.f;
  if (t < 127) {
    float ti = tv[t], si = sv[t], tr = 0.f, sr = 0.f;
    for (int j = 0; j < 127; ++j) {
      tr += fmaxf(ti - tv[j], 0.f);
      sr += fmaxf(si - sv[j], 0.f);
    }
    float d = tr - sr;
    val = d * d;
  }
  for (int off = 32; off; off >>= 1) val += __shfl_xor(val, off);
  int lane = t & 63, w = t >> 6;
  if (lane == 0) red[w] = val;
  __syncthreads();
  if (t == 0) {
    float sum = red[0] + red[1];
    float contrib =
        (1.0f / 256.0f) * fabsf(s_value[b * TOPK] - t_value[b * TOPK]) +
        (1.0f / (127.0f * 256.0f)) * sqrtf(sum);
    atomicAdd(out, contrib);
  }
}

// ---------------- launch ----------------------------------------------------
extern "C" void kernel_launch(void* const* d_in, const int* in_sizes, int n_in,
                              void* d_out, int out_size, void* d_ws,
                              size_t ws_size, hipStream_t stream) {
  const float* f_s = (const float*)d_in[0];
  const float* f_t = (const float*)d_in[1];
  const float* gallery = (const float*)d_in[2];
  float* out = (float*)d_out;

  // workspace layout (~52.9 MB)
  float* d2 = (float*)d_ws;                               // 512*8192 f32
  short* Abf = (short*)(d2 + (size_t)512 * NTOT);         // 512*2048 bf16
  short* Bbf = Abf + (size_t)512 * DDIM;                  // 8192*2048 bf16
  float* normA = (float*)(Bbf + (size_t)NTOT * DDIM);     // 512
  float* galnorm = normA + 512;                           // 8192
  float* t_value = galnorm + NTOT;                        // 256*128
  float* s_value = t_value + BDIM * TOPK;                 // 256*128
  int* topidx = (int*)(s_value + BDIM * TOPK);            // 256*128

  hipMemsetAsync(d_out, 0, sizeof(float), stream);

  k_prep<<<BDIM, 256, 0, stream>>>(f_t, f_s, Abf, Bbf, normA, galnorm);
  k_galn<<<NGAL / 4, 256, 0, stream>>>(gallery, Bbf, galnorm);
  k_gemm<<<dim3(NTOT / 128, 512 / 128), 256, 0, stream>>>(Abf, Bbf, normA,
                                                          galnorm, d2);
  k_topk<<<BDIM, 256, 0, stream>>>(d2, t_value, topidx);
  k_sg<<<BDIM, 128, 0, stream>>>(d2, topidx, s_value);
  k_loss<<<BDIM, 128, 0, stream>>>(t_value, s_value, out);
}

// Round 3
// 174.867 us; speedup vs baseline: 2.9876x; 1.0422x over previous
//
#include <hip/hip_runtime.h>
#include <hip/hip_bf16.h>

// B=256, d=2048, N0=7936, N=8192, K=128, P=2, ALPHA=BETA=1, EPS=1e-12
#define BDIM 256
#define DDIM 2048
#define NGAL 7936
#define NTOT 8192
#define TOPK 128
#define EPSC 1e-12f

typedef __attribute__((ext_vector_type(8))) short bf16x8;
typedef __attribute__((ext_vector_type(4))) float f32x4;
typedef unsigned long long u64;

// round-to-nearest-even fp32 -> bf16 (bit pattern in a short)
__device__ __forceinline__ short bfr(float x) {
  unsigned u = __float_as_uint(x);
  unsigned r = (u + 0x7FFFu + ((u >> 16) & 1u)) >> 16;
  return (short)r;
}

// ---------------- Kernel 1: teacher/student squares, norms, bf16 A rows ----
__global__ __launch_bounds__(256) void k_prep(
    const float* __restrict__ f_t, const float* __restrict__ f_s,
    short* __restrict__ Abf, short* __restrict__ Bbf,
    float* __restrict__ normA, float* __restrict__ galnorm) {
  int b = blockIdx.x, t = threadIdx.x;
  const float4* t4 = (const float4*)(f_t + (size_t)b * DDIM);
  const float4* s4 = (const float4*)(f_s + (size_t)b * DDIM);
  float st = 0.f, ss = 0.f;
  for (int i = t; i < DDIM / 4; i += 256) {
    float4 v = t4[i];
    float4 q = make_float4(v.x * v.x, v.y * v.y, v.z * v.z, v.w * v.w);
    short4 qb = make_short4(bfr(q.x), bfr(q.y), bfr(q.z), bfr(q.w));
    *(short4*)&Abf[(size_t)b * DDIM + i * 4] = qb;
    *(short4*)&Bbf[(size_t)(NGAL + b) * DDIM + i * 4] = qb;
    st += q.x * q.x + q.y * q.y + q.z * q.z + q.w * q.w;
    float4 u_ = s4[i];
    float4 r = make_float4(u_.x * u_.x, u_.y * u_.y, u_.z * u_.z, u_.w * u_.w);
    *(short4*)&Abf[(size_t)(BDIM + b) * DDIM + i * 4] =
        make_short4(bfr(r.x), bfr(r.y), bfr(r.z), bfr(r.w));
    ss += r.x * r.x + r.y * r.y + r.z * r.z + r.w * r.w;
  }
  for (int off = 32; off; off >>= 1) {
    st += __shfl_xor(st, off);
    ss += __shfl_xor(ss, off);
  }
  __shared__ float red[8];
  int lane = t & 63, wv = t >> 6;
  if (lane == 0) { red[wv] = st; red[4 + wv] = ss; }
  __syncthreads();
  if (t == 0) {
    float a = red[0] + red[1] + red[2] + red[3];
    float c = red[4] + red[5] + red[6] + red[7];
    normA[b] = a;
    galnorm[NGAL + b] = a;
    normA[BDIM + b] = c;
  }
}

// ---------------- Kernel 2: gallery -> bf16 rows + norms (1 wave/row) ------
__global__ __launch_bounds__(256) void k_galn(
    const float* __restrict__ gallery, short* __restrict__ Bbf,
    float* __restrict__ galnorm) {
  int row = blockIdx.x * 4 + (threadIdx.x >> 6);
  int lane = threadIdx.x & 63;
  const float4* g4 = (const float4*)(gallery + (size_t)row * DDIM);
  float s = 0.f;
  for (int i = lane; i < DDIM / 4; i += 64) {
    float4 v = g4[i];
    *(short4*)&Bbf[(size_t)row * DDIM + i * 4] =
        make_short4(bfr(v.x), bfr(v.y), bfr(v.z), bfr(v.w));
    s += v.x * v.x + v.y * v.y + v.z * v.z + v.w * v.w;
  }
  for (int off = 32; off; off >>= 1) s += __shfl_xor(s, off);
  if (lane == 0) galnorm[row] = s;
}

// ---------------- Kernel 3: bf16 MFMA GEMM -> clipped squared distances ----
// 64(M)x128(N) tile, BK=64, 4 waves (2x2, wave tile 32x64), double-buffered
// LDS staged via global_load_lds with pre-swizzled global source (linear LDS
// dest = wave-uniform base + lane*16; read side applies the same XOR).
__global__ __launch_bounds__(256) void k_gemm(
    const short* __restrict__ Abf, const short* __restrict__ Bbf,
    const float* __restrict__ normA, const float* __restrict__ galnorm,
    float* __restrict__ d2) {
  __shared__ short S[2][12288];  // [0,4096): A 64x64 ; [4096,12288): B 128x64
  int t = threadIdx.x;
  int n0 = blockIdx.x * 128, m0 = blockIdx.y * 64;
  int lane = t & 63, wid = t >> 6;
  int wm = wid >> 1, wn = wid & 1;

  // staging: 1536 16B chunks, 6 per thread; chunk c -> LDS short-offset c*8
  const short* gb[6];
  int lof[6];
#pragma unroll
  for (int q = 0; q < 6; ++q) {
    int c = t + q * 256;
    int r, j;
    const short* base;
    if (c < 512) {  // A region: 64 rows x 8 chunks
      r = c >> 3; j = c & 7;
      base = Abf + (size_t)(m0 + r) * DDIM;
    } else {        // B region: 128 rows x 8 chunks
      int cb = c - 512;
      r = cb >> 3; j = cb & 7;
      base = Bbf + (size_t)(n0 + r) * DDIM;
    }
    gb[q] = base + ((j * 8) ^ ((r & 7) << 3));  // pre-swizzled global column
    lof[q] = c * 8;
  }

  int fr = lane & 15, fk = (lane >> 4) * 8;
  int axor = (fr & 7) << 3;
  f32x4 acc[2][4] = {};

#define STAGE(buf, kt)                                                       \
  {                                                                          \
    _Pragma("unroll") for (int q = 0; q < 6; ++q)                            \
        __builtin_amdgcn_global_load_lds(                                    \
            (const __attribute__((address_space(1))) void*)(gb[q] + (kt)),   \
            (__attribute__((address_space(3))) void*)(&S[buf][lof[q]]), 16,  \
            0, 0);                                                           \
  }

  STAGE(0, 0);
  __syncthreads();
  int cur = 0;
  for (int it = 0; it < DDIM / 64; ++it) {
    if (it + 1 < DDIM / 64) STAGE(cur ^ 1, (it + 1) * 64);
#pragma unroll
    for (int ks = 0; ks < 2; ++ks) {
      int ko = (ks * 32 + fk) ^ axor;
      bf16x8 av[2], bv[4];
#pragma unroll
      for (int mi = 0; mi < 2; ++mi)
        av[mi] = *(const bf16x8*)&S[cur][(wm * 32 + mi * 16 + fr) * 64 + ko];
#pragma unroll
      for (int ni = 0; ni < 4; ++ni)
        bv[ni] =
            *(const bf16x8*)&S[cur][4096 + (wn * 64 + ni * 16 + fr) * 64 + ko];
#pragma unroll
      for (int mi = 0; mi < 2; ++mi)
#pragma unroll
        for (int ni = 0; ni < 4; ++ni)
          acc[mi][ni] = __builtin_amdgcn_mfma_f32_16x16x32_bf16(
              av[mi], bv[ni], acc[mi][ni], 0, 0, 0);
    }
    __syncthreads();  // drains gload_lds (vmcnt) + lds reads; swap safe
    cur ^= 1;
  }
  // epilogue: C/D map col=lane&15 (n), row=(lane>>4)*4+reg (m)
  int rrow = (lane >> 4) * 4;
#pragma unroll
  for (int mi = 0; mi < 2; ++mi) {
#pragma unroll
    for (int r = 0; r < 4; ++r) {
      int m = m0 + wm * 32 + mi * 16 + rrow + r;
      float nm = normA[m];
#pragma unroll
      for (int ni = 0; ni < 4; ++ni) {
        int n = n0 + wn * 64 + ni * 16 + fr;
        float v = nm + galnorm[n] - 2.0f * acc[mi][ni][r];
        v = fmaxf(v, EPSC);
        if (m < BDIM && n == NGAL + m) v = EPSC;  // exact self-match pin
        d2[(size_t)m * NTOT + n] = v;
      }
    }
  }
#undef STAGE
}

// ---------------- Kernel 4: exact top-128 radix select on unique keys ------
// key = (u32bits(d2) << 13) | idx  (45 bits, unique) -> select all <= kstar
// (exactly 128). Unordered output; also gathers student distances (fused).
__global__ __launch_bounds__(256) void k_topk(
    const float* __restrict__ d2, float* __restrict__ t_value,
    float* __restrict__ s_value, int* __restrict__ topidx) {
  __shared__ unsigned rowu[NTOT];     // 32 KB (bit patterns)
  __shared__ unsigned hist[2][4096];  // 32 KB, 2 copies to halve contention
  __shared__ unsigned wsum[4];
  __shared__ u64 s_pref;
  __shared__ unsigned s_kneed, s_cnt;
  int b = blockIdx.x, t = threadIdx.x;
  int lane = t & 63, w = t >> 6;
  const uint4* r4 = (const uint4*)(d2 + (size_t)b * NTOT);
  uint4* rv4 = (uint4*)rowu;
  for (int i = t; i < NTOT / 4; i += 256) rv4[i] = r4[i];
  if (t == 0) { s_pref = 0; s_kneed = TOPK; s_cnt = 0; }

  const int shs[4] = {33, 21, 9, 0};
  const int bts[4] = {12, 12, 12, 9};
#pragma unroll 1
  for (int p = 0; p < 4; ++p) {
    int sh = shs[p], bits = bts[p];
    unsigned nb = 1u << bits;
    for (int i = t; i < 8192; i += 256) hist[0][i] = 0;  // zero both copies
    __syncthreads();  // zero + rowu + prev-pass winner visible
    u64 pref = s_pref;
    unsigned kn = s_kneed;
    int sh_hi = sh + bits;
#pragma unroll 1
    for (int s = 0; s < NTOT / 256; ++s) {
      int i = t + s * 256;
      u64 key = ((u64)rowu[i] << 13) | (unsigned)i;
      if ((key >> sh_hi) == pref)
        atomicAdd(&hist[w & 1][(unsigned)(key >> sh) & (nb - 1)], 1u);
    }
    __syncthreads();
    unsigned nbper = nb >> 8;
    unsigned base = t * nbper, ls = 0;
    for (unsigned j = 0; j < nbper; ++j)
      ls += hist[0][base + j] + hist[1][base + j];
    unsigned incl = ls;
    for (int off = 1; off < 64; off <<= 1) {
      unsigned x = __shfl_up(incl, off);
      if (lane >= off) incl += x;
    }
    if (lane == 63) wsum[w] = incl;
    __syncthreads();
    unsigned woff = 0;
    for (int ww = 0; ww < w; ++ww) woff += wsum[ww];
    incl += woff;
    unsigned excl = incl - ls;
    if (excl < kn && kn <= incl) {  // unique winner thread
      unsigned re = excl, binj = 0;
      for (unsigned j = 0; j < nbper; ++j) {
        unsigned h = hist[0][base + j] + hist[1][base + j];
        if (kn <= re + h) { binj = base + j; break; }
        re += h;
      }
      s_pref = (pref << bits) | binj;
      s_kneed = kn - re;
    }
    __syncthreads();
  }
  u64 kstar = s_pref;  // exact 128th-smallest key
  const float* srow = d2 + (size_t)(BDIM + b) * NTOT;
#pragma unroll 1
  for (int s = 0; s < NTOT / 256; ++s) {
    int i = t + s * 256;
    unsigned u = rowu[i];
    u64 key = ((u64)u << 13) | (unsigned)i;
    if (key <= kstar) {
      unsigned pos = atomicAdd(&s_cnt, 1u);
      t_value[b * TOPK + pos] = sqrtf(__uint_as_float(u));
      s_value[b * TOPK + pos] = sqrtf(srow[i]);
      topidx[b * TOPK + pos] = i;
    }
  }
}

// ---------------- Kernel 5: loss (order-free: pairing + min-pair exclusion) -
__global__ __launch_bounds__(128) void k_loss(
    const float* __restrict__ t_value, const float* __restrict__ s_value,
    const int* __restrict__ topidx, float* __restrict__ out) {
  int b = blockIdx.x, t = threadIdx.x;
  float tv = t_value[b * TOPK + t], sv = s_value[b * TOPK + t];
  int idx = topidx[b * TOPK + t];
  u64 key = ((u64)__float_as_uint(tv) << 13) | (unsigned)idx;
  u64 m_ = key;
  for (int off = 1; off < 64; off <<= 1) {
    u64 o = __shfl_xor(m_, off);
    if (o < m_) m_ = o;
  }
  __shared__ u64 wmin[2];
  __shared__ float tvs[TOPK], svs[TOPK], red[2], tm_s, sm_s;
  int lane = t & 63, w = t >> 6;
  if (lane == 0) wmin[w] = m_;
  tvs[t] = tv;
  svs[t] = sv;
  __syncthreads();
  u64 kmin = wmin[0] < wmin[1] ? wmin[0] : wmin[1];
  bool ismin = (key == kmin);  // unique (keys unique)
  if (ismin) { tm_s = tv; sm_s = sv; }
  __syncthreads();
  float tmv = tm_s, smv = sm_s;
  float tr = 0.f, sr = 0.f;
  for (int j = 0; j < TOPK; ++j) {
    tr += fmaxf(tv - tvs[j], 0.f);
    sr += fmaxf(sv - svs[j], 0.f);
  }
  tr -= fmaxf(tv - tmv, 0.f);  // exclude the min pair from the rank set
  sr -= fmaxf(sv - smv, 0.f);
  float d = tr - sr;
  float val = ismin ? 0.f : d * d;
  for (int off = 1; off < 64; off <<= 1) val += __shfl_xor(val, off);
  if (lane == 0) red[w] = val;
  __syncthreads();
  if (t == 0) {
    float sum = red[0] + red[1];
    float contrib = (1.f / 256.f) * fabsf(smv - tmv) +
                    (1.f / (127.f * 256.f)) * sqrtf(sum);
    atomicAdd(out, contrib);
  }
}

// ---------------- launch ----------------------------------------------------
extern "C" void kernel_launch(void* const* d_in, const int* in_sizes, int n_in,
                              void* d_out, int out_size, void* d_ws,
                              size_t ws_size, hipStream_t stream) {
  const float* f_s = (const float*)d_in[0];
  const float* f_t = (const float*)d_in[1];
  const float* gallery = (const float*)d_in[2];
  float* out = (float*)d_out;

  float* d2 = (float*)d_ws;                            // 512*8192 f32
  short* Abf = (short*)(d2 + (size_t)512 * NTOT);      // 512*2048 bf16
  short* Bbf = Abf + (size_t)512 * DDIM;               // 8192*2048 bf16
  float* normA = (float*)(Bbf + (size_t)NTOT * DDIM);  // 512
  float* galnorm = normA + 512;                        // 8192
  float* t_value = galnorm + NTOT;                     // 256*128
  float* s_value = t_value + BDIM * TOPK;              // 256*128
  int* topidx = (int*)(s_value + BDIM * TOPK);         // 256*128

  hipMemsetAsync(d_out, 0, sizeof(float), stream);

  k_prep<<<BDIM, 256, 0, stream>>>(f_t, f_s, Abf, Bbf, normA, galnorm);
  k_galn<<<NGAL / 4, 256, 0, stream>>>(gallery, Bbf, galnorm);
  k_gemm<<<dim3(NTOT / 128, 512 / 64), 256, 0, stream>>>(Abf, Bbf, normA,
                                                         galnorm, d2);
  k_topk<<<BDIM, 256, 0, stream>>>(d2, t_value, s_value, topidx);
  k_loss<<<BDIM, 128, 0, stream>>>(t_value, s_value, topidx, out);
}

// Round 4
// 159.308 us; speedup vs baseline: 3.2794x; 1.0977x over previous
//
#include <hip/hip_runtime.h>
#include <hip/hip_bf16.h>

// B=256, d=2048, N0=7936, N=8192, K=128, P=2, ALPHA=BETA=1, EPS=1e-12
#define BDIM 256
#define DDIM 2048
#define NGAL 7936
#define NTOT 8192
#define TOPK 128
#define EPSC 1e-12f

typedef __attribute__((ext_vector_type(8))) short bf16x8;
typedef __attribute__((ext_vector_type(4))) float f32x4;
typedef unsigned long long u64;

// round-to-nearest-even fp32 -> bf16 (bit pattern in a short)
__device__ __forceinline__ short bfr(float x) {
  unsigned u = __float_as_uint(x);
  unsigned r = (u + 0x7FFFu + ((u >> 16) & 1u)) >> 16;
  return (short)r;
}

// ---------------- Kernel 1: gallery bf16+norms  +  teacher/student prep ----
// blocks [0, NGAL/4): gallery rows (1 wave each, 4 rows/block)
// blocks [NGAL/4, NGAL/4+256): prep row b (squares, norms, bf16 A rows)
__global__ __launch_bounds__(256) void k_prep_gal(
    const float* __restrict__ f_t, const float* __restrict__ f_s,
    const float* __restrict__ gallery, short* __restrict__ Abf,
    short* __restrict__ Bbf, float* __restrict__ normA,
    float* __restrict__ galnorm) {
  int bx = blockIdx.x, t = threadIdx.x;
  int lane = t & 63, wv = t >> 6;
  if (bx < NGAL / 4) {
    int row = bx * 4 + wv;
    const float4* g4 = (const float4*)(gallery + (size_t)row * DDIM);
    float s = 0.f;
    for (int i = lane; i < DDIM / 4; i += 64) {
      float4 v = g4[i];
      *(short4*)&Bbf[(size_t)row * DDIM + i * 4] =
          make_short4(bfr(v.x), bfr(v.y), bfr(v.z), bfr(v.w));
      s += v.x * v.x + v.y * v.y + v.z * v.z + v.w * v.w;
    }
    for (int off = 32; off; off >>= 1) s += __shfl_xor(s, off);
    if (lane == 0) galnorm[row] = s;
    return;
  }
  int b = bx - NGAL / 4;
  const float4* t4 = (const float4*)(f_t + (size_t)b * DDIM);
  const float4* s4 = (const float4*)(f_s + (size_t)b * DDIM);
  float st = 0.f, ss = 0.f;
  for (int i = t; i < DDIM / 4; i += 256) {
    float4 v = t4[i];
    float4 q = make_float4(v.x * v.x, v.y * v.y, v.z * v.z, v.w * v.w);
    short4 qb = make_short4(bfr(q.x), bfr(q.y), bfr(q.z), bfr(q.w));
    *(short4*)&Abf[(size_t)b * DDIM + i * 4] = qb;
    *(short4*)&Bbf[(size_t)(NGAL + b) * DDIM + i * 4] = qb;
    st += q.x * q.x + q.y * q.y + q.z * q.z + q.w * q.w;
    float4 u_ = s4[i];
    float4 r = make_float4(u_.x * u_.x, u_.y * u_.y, u_.z * u_.z, u_.w * u_.w);
    *(short4*)&Abf[(size_t)(BDIM + b) * DDIM + i * 4] =
        make_short4(bfr(r.x), bfr(r.y), bfr(r.z), bfr(r.w));
    ss += r.x * r.x + r.y * r.y + r.z * r.z + r.w * r.w;
  }
  for (int off = 32; off; off >>= 1) {
    st += __shfl_xor(st, off);
    ss += __shfl_xor(ss, off);
  }
  __shared__ float red[8];
  if (lane == 0) { red[wv] = st; red[4 + wv] = ss; }
  __syncthreads();
  if (t == 0) {
    float a = red[0] + red[1] + red[2] + red[3];
    float c = red[4] + red[5] + red[6] + red[7];
    normA[b] = a;
    galnorm[NGAL + b] = a;
    normA[BDIM + b] = c;
  }
}

// ---------------- Kernel 2: bf16 MFMA GEMM -> clipped squared distances ----
// 64(M)x128(N) tile, BK=64, 4 waves (2x2), double-buffered LDS via
// global_load_lds (linear dest; pre-swizzled global source; swizzled reads).
__global__ __launch_bounds__(256) void k_gemm(
    const short* __restrict__ Abf, const short* __restrict__ Bbf,
    const float* __restrict__ normA, const float* __restrict__ galnorm,
    float* __restrict__ d2) {
  __shared__ short S[2][12288];  // [0,4096): A 64x64 ; [4096,12288): B 128x64
  int t = threadIdx.x;
  int n0 = blockIdx.x * 128, m0 = blockIdx.y * 64;
  int lane = t & 63, wid = t >> 6;
  int wm = wid >> 1, wn = wid & 1;

  const short* gb[6];
  int lof[6];
#pragma unroll
  for (int q = 0; q < 6; ++q) {
    int c = t + q * 256;
    int r, j;
    const short* base;
    if (c < 512) {
      r = c >> 3; j = c & 7;
      base = Abf + (size_t)(m0 + r) * DDIM;
    } else {
      int cb = c - 512;
      r = cb >> 3; j = cb & 7;
      base = Bbf + (size_t)(n0 + r) * DDIM;
    }
    gb[q] = base + ((j * 8) ^ ((r & 7) << 3));
    lof[q] = c * 8;
  }

  int fr = lane & 15, fk = (lane >> 4) * 8;
  int axor = (fr & 7) << 3;
  f32x4 acc[2][4] = {};

#define STAGE(buf, kt)                                                       \
  {                                                                          \
    _Pragma("unroll") for (int q = 0; q < 6; ++q)                            \
        __builtin_amdgcn_global_load_lds(                                    \
            (const __attribute__((address_space(1))) void*)(gb[q] + (kt)),   \
            (__attribute__((address_space(3))) void*)(&S[buf][lof[q]]), 16,  \
            0, 0);                                                           \
  }

  STAGE(0, 0);
  __syncthreads();
  int cur = 0;
  for (int it = 0; it < DDIM / 64; ++it) {
    if (it + 1 < DDIM / 64) STAGE(cur ^ 1, (it + 1) * 64);
#pragma unroll
    for (int ks = 0; ks < 2; ++ks) {
      int ko = (ks * 32 + fk) ^ axor;
      bf16x8 av[2], bv[4];
#pragma unroll
      for (int mi = 0; mi < 2; ++mi)
        av[mi] = *(const bf16x8*)&S[cur][(wm * 32 + mi * 16 + fr) * 64 + ko];
#pragma unroll
      for (int ni = 0; ni < 4; ++ni)
        bv[ni] =
            *(const bf16x8*)&S[cur][4096 + (wn * 64 + ni * 16 + fr) * 64 + ko];
#pragma unroll
      for (int mi = 0; mi < 2; ++mi)
#pragma unroll
        for (int ni = 0; ni < 4; ++ni)
          acc[mi][ni] = __builtin_amdgcn_mfma_f32_16x16x32_bf16(
              av[mi], bv[ni], acc[mi][ni], 0, 0, 0);
    }
    __syncthreads();
    cur ^= 1;
  }
  int rrow = (lane >> 4) * 4;
#pragma unroll
  for (int mi = 0; mi < 2; ++mi) {
#pragma unroll
    for (int r = 0; r < 4; ++r) {
      int m = m0 + wm * 32 + mi * 16 + rrow + r;
      float nm = normA[m];
#pragma unroll
      for (int ni = 0; ni < 4; ++ni) {
        int n = n0 + wn * 64 + ni * 16 + fr;
        float v = nm + galnorm[n] - 2.0f * acc[mi][ni][r];
        v = fmaxf(v, EPSC);
        if (m < BDIM && n == NGAL + m) v = EPSC;  // exact self-match pin
        d2[(size_t)m * NTOT + n] = v;
      }
    }
  }
#undef STAGE
}

// ---------------- Kernel 3: per-chunk exact top-128 radix select -----------
// Block (c, b): columns [c*2048,(c+1)*2048) of teacher row b. Unique 43-bit
// keys (u32<<11)|local_idx, 4 passes x 11 bits, 2048-bin hist (2 wave-parity
// copies, permuted slots for conflict-free summation). Emits exactly 128
// unordered u64 keys (u32<<13)|global_idx per chunk.
__global__ __launch_bounds__(256) void k_part(
    const float* __restrict__ d2, u64* __restrict__ cand) {
  __shared__ unsigned rowu[2048];
  __shared__ unsigned hist[2][2048];
  __shared__ unsigned wsum[4];
  __shared__ u64 s_pref;
  __shared__ unsigned s_kneed, s_cnt;
  int c = blockIdx.x, b = blockIdx.y, t = threadIdx.x;
  int lane = t & 63, w = t >> 6;
  const uint4* src = (const uint4*)(d2 + (size_t)b * NTOT + c * 2048);
  ((uint4*)rowu)[t] = src[t];
  ((uint4*)rowu)[t + 256] = src[t + 256];
  if (t == 0) { s_pref = 0; s_kneed = TOPK; s_cnt = 0; }
#pragma unroll 1
  for (int p = 0; p < 4; ++p) {
    int sh = 33 - 11 * p;
    for (int i = t; i < 4096; i += 256) (&hist[0][0])[i] = 0;
    __syncthreads();  // zero + rowu + prev winner visible
    u64 pref = s_pref;
    unsigned kn = s_kneed;
#pragma unroll
    for (int s = 0; s < 8; ++s) {
      int i = t + s * 256;
      u64 key = ((u64)rowu[i] << 11) | (unsigned)i;
      if ((key >> (sh + 11)) == pref) {
        unsigned bin = (unsigned)(key >> sh) & 2047u;
        unsigned slot = ((bin & 7u) << 8) | (bin >> 3);  // conflict-free sums
        atomicAdd(&hist[w & 1][slot], 1u);
      }
    }
    __syncthreads();
    unsigned ls = 0;  // sum of bins [8t, 8t+8) == slots q*256+t
#pragma unroll
    for (int q = 0; q < 8; ++q)
      ls += hist[0][q * 256 + t] + hist[1][q * 256 + t];
    unsigned incl = ls;
    for (int off = 1; off < 64; off <<= 1) {
      unsigned x = __shfl_up(incl, off);
      if (lane >= off) incl += x;
    }
    if (lane == 63) wsum[w] = incl;
    __syncthreads();
    unsigned woff = 0;
    for (int ww = 0; ww < w; ++ww) woff += wsum[ww];
    incl += woff;
    unsigned excl = incl - ls;
    if (excl < kn && kn <= incl) {  // unique winner thread
      unsigned re = excl, binj = 0;
      for (int q = 0; q < 8; ++q) {
        unsigned h = hist[0][q * 256 + t] + hist[1][q * 256 + t];
        if (kn <= re + h) { binj = ((unsigned)t << 3) | (unsigned)q; break; }
        re += h;
      }
      s_pref = (pref << 11) | binj;
      s_kneed = kn - re;
    }
    __syncthreads();
  }
  u64 kstar = s_pref;  // exact 128th-smallest key of this chunk
  u64* dst = cand + ((size_t)b * 4 + c) * TOPK;
#pragma unroll
  for (int s = 0; s < 8; ++s) {
    int i = t + s * 256;
    unsigned u = rowu[i];
    u64 key = ((u64)u << 11) | (unsigned)i;
    if (key <= kstar) {
      unsigned pos = atomicAdd(&s_cnt, 1u);
      dst[pos] = ((u64)u << 13) | (unsigned)(c * 2048 + i);
    }
  }
}

// ---------------- Kernel 4: merge 512 candidates + loss --------------------
// Bitonic-sort 512 unique keys (value,idx) ascending == reference order;
// first 128 are the row's top-k. Gather student d2, compute loss directly.
__global__ __launch_bounds__(256) void k_mloss(
    const u64* __restrict__ cand, const float* __restrict__ d2,
    float* __restrict__ out) {
  __shared__ u64 sk[512];
  __shared__ float tvs[TOPK], svs[TOPK], red[4];
  int b = blockIdx.x, t = threadIdx.x;
  sk[t] = cand[(size_t)b * 512 + t];
  sk[t + 256] = cand[(size_t)b * 512 + 256 + t];
  __syncthreads();
  for (int len = 2; len <= 512; len <<= 1) {
    for (int inc = len >> 1; inc; inc >>= 1) {
      int low = t & (inc - 1);
      int i0 = ((t - low) << 1) | low, i1 = i0 + inc;
      u64 a = sk[i0], c2 = sk[i1];
      bool asc = (i0 & len) == 0;
      if ((a > c2) == asc) { sk[i0] = c2; sk[i1] = a; }
      __syncthreads();
    }
  }
  float tv = 0.f, sv = 0.f;
  const float* srow = d2 + (size_t)(BDIM + b) * NTOT;
  if (t < TOPK) {
    u64 key = sk[t];
    tv = sqrtf(__uint_as_float((unsigned)(key >> 13)));
    sv = sqrtf(srow[(unsigned)(key & 8191u)]);
    tvs[t] = tv;
    svs[t] = sv;
  }
  __syncthreads();
  float val = 0.f;
  if (t >= 1 && t < TOPK) {
    float tr = 0.f, sr = 0.f;
    for (int j = 1; j < TOPK; ++j) {
      tr += fmaxf(tv - tvs[j], 0.f);
      sr += fmaxf(sv - svs[j], 0.f);
    }
    float d = tr - sr;
    val = d * d;
  }
  int lane = t & 63, w = t >> 6;
  for (int off = 1; off < 64; off <<= 1) val += __shfl_xor(val, off);
  if (lane == 0) red[w] = val;
  __syncthreads();
  if (t == 0) {
    float sum = red[0] + red[1] + red[2] + red[3];
    float contrib = (1.f / 256.f) * fabsf(svs[0] - tvs[0]) +
                    (1.f / (127.f * 256.f)) * sqrtf(sum);
    atomicAdd(out, contrib);
  }
}

// ---------------- launch ----------------------------------------------------
extern "C" void kernel_launch(void* const* d_in, const int* in_sizes, int n_in,
                              void* d_out, int out_size, void* d_ws,
                              size_t ws_size, hipStream_t stream) {
  const float* f_s = (const float*)d_in[0];
  const float* f_t = (const float*)d_in[1];
  const float* gallery = (const float*)d_in[2];
  float* out = (float*)d_out;

  float* d2 = (float*)d_ws;                            // 512*8192 f32 (16 MB)
  short* Abf = (short*)(d2 + (size_t)512 * NTOT);      // 512*2048 bf16 (2 MB)
  short* Bbf = Abf + (size_t)512 * DDIM;               // 8192*2048 bf16 (32 MB)
  float* normA = (float*)(Bbf + (size_t)NTOT * DDIM);  // 512
  float* galnorm = normA + 512;                        // 8192
  u64* cand = (u64*)(galnorm + NTOT);                  // 256*512 u64 (1 MB)

  hipMemsetAsync(d_out, 0, sizeof(float), stream);

  k_prep_gal<<<NGAL / 4 + BDIM, 256, 0, stream>>>(f_t, f_s, gallery, Abf, Bbf,
                                                  normA, galnorm);
  k_gemm<<<dim3(NTOT / 128, 512 / 64), 256, 0, stream>>>(Abf, Bbf, normA,
                                                         galnorm, d2);
  k_part<<<dim3(4, BDIM), 256, 0, stream>>>(d2, cand);
  k_mloss<<<BDIM, 256, 0, stream>>>(cand, d2, out);
}